// Round 2
// baseline (578.228 us; speedup 1.0000x reference)
//
#include <hip/hip_runtime.h>
#include <hip/hip_bf16.h>
#include <math.h>

// Problem constants
#define S_LEN 2048
#define HIDDEN 4096
#define N_HEADS 32
#define N_KV 8
#define HEAD_DIM 128

typedef __attribute__((ext_vector_type(8))) short short8;   // 8 bf16 = 4 VGPRs
typedef __attribute__((ext_vector_type(4))) float f32x4;    // MFMA C/D frag

typedef __attribute__((address_space(3))) unsigned int as3_u32;
typedef const __attribute__((address_space(1))) unsigned int as1_u32;

__device__ __forceinline__ void gload16(const void* g, void* lds) {
  __builtin_amdgcn_global_load_lds((as1_u32*)g, (as3_u32*)lds, 16, 0, 0);
}

__device__ __forceinline__ unsigned short f2bf(float f) {
  unsigned int u = __float_as_uint(f);
  return (unsigned short)((u + 0x7fff + ((u >> 16) & 1)) >> 16);  // RNE
}
__device__ __forceinline__ float bf2f(unsigned short u) {
  return __uint_as_float(((unsigned int)u) << 16);
}

// ---------------------------------------------------------------------------
// fp32 -> bf16 conversion, 4 elems/thread
// ---------------------------------------------------------------------------
__global__ void conv_bf16(const float* __restrict__ in, unsigned short* __restrict__ out, int n) {
  int i = (blockIdx.x * blockDim.x + threadIdx.x) * 4;
  if (i >= n) return;
  float4 v = *(const float4*)&in[i];
  ushort4 o;
  o.x = f2bf(v.x); o.y = f2bf(v.y); o.z = f2bf(v.z); o.w = f2bf(v.w);
  *(ushort4*)&out[i] = o;
}

// ---------------------------------------------------------------------------
// m97-style bf16 MFMA GEMM core: one 128x128 C-tile per 256-thread block.
// ---------------------------------------------------------------------------
__device__ __forceinline__ void storeC(float* C, float v) { *C = v; }
__device__ __forceinline__ void storeC(unsigned short* C, float v) { *C = f2bf(v); }

template <typename OutT>
__device__ __forceinline__ void gemm_core_128(
    const unsigned short* __restrict__ A, const unsigned short* __restrict__ B,
    OutT* __restrict__ C, int K, int ldc) {
  __shared__ unsigned short As[128 * 32];
  __shared__ unsigned short Bs[128 * 32];

  const int tid = threadIdx.x;
  const int w = tid >> 6;
  const int lane = tid & 63;
  const int wr = (w >> 1) * 64;
  const int wc = (w & 1) * 64;
  const int lrow = lane & 15;
  const int lk8 = lane >> 4;

  f32x4 acc[4][4];
#pragma unroll
  for (int i = 0; i < 4; i++)
#pragma unroll
    for (int j = 0; j < 4; j++) acc[i][j] = (f32x4){0.f, 0.f, 0.f, 0.f};

  const int sr = (lane >> 2);
  const int sc = (lane & 3) * 8;

  for (int k0 = 0; k0 < K; k0 += 32) {
    __syncthreads();
#pragma unroll
    for (int s = 0; s < 2; s++) {
      int r = w * 32 + s * 16 + sr;
      gload16(&A[(size_t)r * K + k0 + sc], &As[(w * 32 + s * 16) * 32]);
      gload16(&B[(size_t)r * K + k0 + sc], &Bs[(w * 32 + s * 16) * 32]);
    }
    __syncthreads();

    short8 a[4], b[4];
#pragma unroll
    for (int i = 0; i < 4; i++)
      a[i] = *(const short8*)&As[(wr + i * 16 + lrow) * 32 + lk8 * 8];
#pragma unroll
    for (int j = 0; j < 4; j++)
      b[j] = *(const short8*)&Bs[(wc + j * 16 + lrow) * 32 + lk8 * 8];
#pragma unroll
    for (int i = 0; i < 4; i++)
#pragma unroll
      for (int j = 0; j < 4; j++)
        acc[i][j] = __builtin_amdgcn_mfma_f32_16x16x32_bf16(a[i], b[j], acc[i][j], 0, 0, 0);
  }

#pragma unroll
  for (int i = 0; i < 4; i++)
#pragma unroll
    for (int j = 0; j < 4; j++) {
      int col = wc + j * 16 + lrow;
#pragma unroll
      for (int r = 0; r < 4; r++) {
        int row = wr + i * 16 + lk8 * 4 + r;
        storeC(&C[(size_t)row * ldc + col], acc[i][j][r]);
      }
    }
}

// Fused QKV projection -> bf16 outputs Qb [S,4096], Kb [S,1024], Vb [S,1024]
__global__ __launch_bounds__(256) void gemm_qkv(
    const unsigned short* __restrict__ Xb,
    const unsigned short* __restrict__ Wqb, const unsigned short* __restrict__ Wkb,
    const unsigned short* __restrict__ Wvb,
    unsigned short* __restrict__ Qb, unsigned short* __restrict__ Kb,
    unsigned short* __restrict__ Vb) {
  const int colBase = blockIdx.x * 128;
  const int rowBase = blockIdx.y * 128;
  const unsigned short* B;
  unsigned short* C;
  int ldc, ccol;
  if (colBase < 4096)      { B = Wqb + (size_t)colBase * HIDDEN;          C = Qb; ldc = 4096; ccol = colBase; }
  else if (colBase < 5120) { B = Wkb + (size_t)(colBase - 4096) * HIDDEN; C = Kb; ldc = 1024; ccol = colBase - 4096; }
  else                     { B = Wvb + (size_t)(colBase - 5120) * HIDDEN; C = Vb; ldc = 1024; ccol = colBase - 5120; }
  gemm_core_128(Xb + (size_t)rowBase * HIDDEN, B,
                C + (size_t)rowBase * ldc + ccol, HIDDEN, ldc);
}

// Output projection: [2048,4096](bf16) @ Wo^T -> fp32 out
__global__ __launch_bounds__(256) void gemm_out(
    const unsigned short* __restrict__ Ob, const unsigned short* __restrict__ Wob,
    float* __restrict__ C) {
  const int colBase = blockIdx.x * 128;
  const int rowBase = blockIdx.y * 128;
  gemm_core_128(Ob + (size_t)rowBase * HIDDEN, Wob + (size_t)colBase * HIDDEN,
                C + (size_t)rowBase * HIDDEN + colBase, HIDDEN, HIDDEN);
}

// ---------------------------------------------------------------------------
// RoPE on bf16 Q/K, writing PACKED tile layouts:
//   Qp: per (head, 16-query strip) contiguous 4 KB:
//       Qp[((h*128 + (s>>4))*16 + (s&15))*128 + d]
//   Kp: per (kv head, 64-key tile) contiguous 16 KB:
//       Kp[((kvh*32 + (s>>6))*64 + (s&63))*128 + d]
// Q additionally scaled by 1/sqrt(128) * log2(e)  (exp2-domain softmax).
// ---------------------------------------------------------------------------
#define QSCALE 0.12753102123752056f  // 0.08838834764831845 * 1.4426950408889634

__global__ void rope_kernel(const unsigned short* __restrict__ Q,
                            const unsigned short* __restrict__ K,
                            unsigned short* __restrict__ Qp,
                            unsigned short* __restrict__ Kp) {
  int idx = blockIdx.x * blockDim.x + threadIdx.x;
  int d = idx & 63;
  int sh = idx >> 6;
  int h = sh % (N_HEADS + N_KV);
  int s = sh / (N_HEADS + N_KV);
  if (s >= S_LEN) return;

  float freq = expf(-(float)d * (9.210340371976184f / 64.0f));
  float ang = (float)s * freq;
  float sn, cs;
  sincosf(ang, &sn, &cs);

  const unsigned short* src;
  unsigned short* dst;
  float sc_out;
  if (h < N_HEADS) {
    src = Q + ((size_t)s * N_HEADS + h) * HEAD_DIM;
    dst = Qp + (((size_t)h * 128 + (s >> 4)) * 16 + (s & 15)) * HEAD_DIM;
    sc_out = QSCALE;
  } else {
    int kvh = h - N_HEADS;
    src = K + ((size_t)s * N_KV + kvh) * HEAD_DIM;
    dst = Kp + (((size_t)kvh * 32 + (s >> 6)) * 64 + (s & 63)) * HEAD_DIM;
    sc_out = 1.0f;
  }

  float x1 = bf2f(src[d]);
  float x2 = bf2f(src[d + 64]);
  dst[d] = f2bf((x1 * cs - x2 * sn) * sc_out);
  dst[d + 64] = f2bf((x2 * cs + x1 * sn) * sc_out);
}

// ---------------------------------------------------------------------------
// V transpose into PACKED tiles: Vb [S,1024] -> Vp, per (kvh, 64-key tile)
// contiguous 16 KB of [128 dims][64 keys]:
//   Vp[((kvh*32 + kt)*128 + d)*64 + k]
// ---------------------------------------------------------------------------
__global__ __launch_bounds__(256) void transp_v(
    const unsigned short* __restrict__ Vb, unsigned short* __restrict__ Vp) {
  __shared__ unsigned short t[64][72];
  const int s0 = blockIdx.x * 64;   // key tile base
  const int c0 = blockIdx.y * 64;   // flat dim base (kvh*128 + d)
  const int kt = s0 >> 6;
  const int tid = threadIdx.x;
#pragma unroll
  for (int i = 0; i < 2; i++) {
    int c = tid + i * 256;
    int r = c >> 3, ch = c & 7;
    *(short8*)&t[r][ch * 8] = *(const short8*)&Vb[(size_t)(s0 + r) * 1024 + c0 + ch * 8];
  }
  __syncthreads();
#pragma unroll
  for (int i = 0; i < 4; i++) {
    int c = tid + i * 256;
    int orow = c >> 4, oc4 = (c & 15) * 4;
    int g = c0 + orow;               // flat dim
    int kvh = g >> 7, d = g & 127;
    ushort4 o;
    o.x = t[oc4 + 0][orow]; o.y = t[oc4 + 1][orow];
    o.z = t[oc4 + 2][orow]; o.w = t[oc4 + 3][orow];
    *(ushort4*)&Vp[(((size_t)kvh * 32 + kt) * 128 + d) * 64 + oc4] = o;
  }
}

// ---------------------------------------------------------------------------
// MFMA flash attention v4: gemm-style staging from PACKED contiguous tiles.
// Block = 128 queries x 1 head, 4 waves x 32 queries. K-tiles of 64.
// K (64x128) and V^T (128x64) staged per tile via global_load_lds width=16
// from fully contiguous 16 KB buffers, with a 16B-granular XOR swizzle baked
// into the per-lane SOURCE address so LDS fragment reads are conflict-free
// (LDS dest must stay lane-contiguous -> cannot pad).
//   K LDS:  chunk (row r, pos p) holds global chunk (r, p ^ (r&15))
//   Vt LDS: chunk (row r, pos p) holds global chunk (r, p ^ (r&7))
// Transposed-S softmax (query = lane&15): 2 shuffles per strip, per-lane
// alpha rescale. Grid 512: blocks b and b+256 have complementary qi.
// LDS 50 KB -> 3 blocks/CU.
// ---------------------------------------------------------------------------
#define AK 64
#define PSTR 72

__global__ __launch_bounds__(256, 3) void attn_mfma(
    const unsigned short* __restrict__ Qp, const unsigned short* __restrict__ Kp,
    const unsigned short* __restrict__ Vp, unsigned short* __restrict__ Ob) {
  const int b = blockIdx.x;
  const int h = b & 31;
  const int qi = (b < 256) ? (b >> 5) : (15 - ((b - 256) >> 5));
  const int kvh = h >> 2;

  const int tid = threadIdx.x;
  const int w = tid >> 6;
  const int lane = tid & 63;
  const int lrow = lane & 15;
  const int lk8 = lane >> 4;

  __shared__ unsigned short Ks[64 * 128];      // 16 KB, swizzled
  __shared__ unsigned short Vts[128 * 64];     // 16 KB, swizzled
  __shared__ unsigned short Ps[4 * 32 * PSTR]; // 18 KB, wave-private
  unsigned short* Pw = &Ps[w * 32 * PSTR];

  // ---- Q fragments from packed strips (4 KB contiguous each) ----
  short8 qf[2][4];
  const int t0 = qi * 8 + w * 2;
#pragma unroll
  for (int i = 0; i < 2; i++)
#pragma unroll
    for (int ks = 0; ks < 4; ks++)
      qf[i][ks] = *(const short8*)&Qp[(((size_t)h * 128 + t0 + i) * 16 + lrow) * 128 +
                                      ks * 32 + lk8 * 8];

  f32x4 acc[8][2];  // O^T: [dim-tile][query-strip]
  float m_i[2], l_i[2];
#pragma unroll
  for (int n = 0; n < 8; n++)
#pragma unroll
    for (int i = 0; i < 2; i++) acc[n][i] = (f32x4){0.f, 0.f, 0.f, 0.f};
  m_i[0] = m_i[1] = -1e30f;
  l_i[0] = l_i[1] = 0.f;

  const int nkt = 2 * qi + 2;

  for (int kt = 0; kt < nkt; kt++) {
    const int kb = kt * AK;
    const unsigned short* Kt  = Kp + ((size_t)kvh * 32 + kt) * 8192;
    const unsigned short* Vtt = Vp + ((size_t)kvh * 32 + kt) * 8192;

    __syncthreads();  // all waves done reading previous tile
    // ---- Stage K + V^T (16 KB each) with swizzled contiguous sources ----
#pragma unroll
    for (int j = 0; j < 4; j++) {
      int seg = w * 4 + j;                  // 0..15, 1 KB LDS segment
      // K: lds slot (r = seg*4 + lk8, p = lrow) <- global chunk (r, p^(r&15))
      int kr = seg * 4 + lk8;
      int kc = lrow ^ (kr & 15);
      gload16(Kt + ((size_t)kr * 16 + kc) * 8, &Ks[seg * 512]);
      // Vt: lds slot (r = seg*8 + lane>>3, p = lane&7) <- chunk (r, p^(r&7))
      int vr = seg * 8 + (lane >> 3);
      int vc = (lane & 7) ^ (vr & 7);
      gload16(Vtt + ((size_t)vr * 8 + vc) * 8, &Vts[seg * 512]);
    }
    __syncthreads();  // barrier drains vmcnt -> staged data visible

    // ---- S^T = K Q^T ----
    f32x4 s[2][4];
#pragma unroll
    for (int i = 0; i < 2; i++)
#pragma unroll
      for (int n = 0; n < 4; n++) s[i][n] = (f32x4){0.f, 0.f, 0.f, 0.f};

#pragma unroll
    for (int ks = 0; ks < 4; ks++) {
      short8 kf[4];
#pragma unroll
      for (int n = 0; n < 4; n++)
        kf[n] = *(const short8*)&Ks[(n * 16 + lrow) * 128 + (((ks * 4 + lk8) ^ lrow)) * 8];
#pragma unroll
      for (int i = 0; i < 2; i++)
#pragma unroll
        for (int n = 0; n < 4; n++)
          s[i][n] = __builtin_amdgcn_mfma_f32_16x16x32_bf16(kf[n], qf[i][ks], s[i][n], 0, 0, 0);
    }

    // ---- Causal mask: rows=keys (lk8*4+r), cols=queries (lrow) ----
    const int wqb = qi * 128 + w * 32;
    if (kb + AK - 1 > wqb) {
#pragma unroll
      for (int i = 0; i < 2; i++) {
        int query = wqb + i * 16 + lrow;
#pragma unroll
        for (int n = 0; n < 4; n++) {
          int keyb = kb + n * 16 + lk8 * 4;
#pragma unroll
          for (int r = 0; r < 4; r++)
            if (keyb + r > query) s[i][n][r] = -1e30f;
        }
      }
    }

    // ---- Online softmax (exp2): 16 in-lane scores + 2 shuffles per strip ----
#pragma unroll
    for (int i = 0; i < 2; i++) {
      float mx = -1e30f;
#pragma unroll
      for (int n = 0; n < 4; n++)
#pragma unroll
        for (int r = 0; r < 4; r++) mx = fmaxf(mx, s[i][n][r]);
      mx = fmaxf(mx, __shfl_xor(mx, 16, 64));
      mx = fmaxf(mx, __shfl_xor(mx, 32, 64));
      float mn = fmaxf(m_i[i], mx);
      float al = exp2f(m_i[i] - mn);
      m_i[i] = mn;
      float ls = 0.f;
#pragma unroll
      for (int n = 0; n < 4; n++)
#pragma unroll
        for (int r = 0; r < 4; r++) {
          float e = exp2f(s[i][n][r] - mn);
          s[i][n][r] = e;
          ls += e;
        }
      ls += __shfl_xor(ls, 16, 64);
      ls += __shfl_xor(ls, 32, 64);
      l_i[i] = l_i[i] * al + ls;
#pragma unroll
      for (int n = 0; n < 8; n++)
#pragma unroll
        for (int r = 0; r < 4; r++) acc[n][i][r] *= al;
    }

    // ---- P -> wave-private LDS [query][key] ----
#pragma unroll
    for (int i = 0; i < 2; i++)
#pragma unroll
      for (int n = 0; n < 4; n++) {
        ushort4 pk;
        pk.x = f2bf(s[i][n][0]); pk.y = f2bf(s[i][n][1]);
        pk.z = f2bf(s[i][n][2]); pk.w = f2bf(s[i][n][3]);
        *(ushort4*)&Pw[(i * 16 + lrow) * PSTR + n * 16 + lk8 * 4] = pk;
      }

    // ---- O^T += V^T P^T ----
#pragma unroll
    for (int ks2 = 0; ks2 < 2; ks2++) {
      short8 pf[2];
#pragma unroll
      for (int i = 0; i < 2; i++)
        pf[i] = *(const short8*)&Pw[(i * 16 + lrow) * PSTR + ks2 * 32 + lk8 * 8];
#pragma unroll
      for (int n = 0; n < 8; n++) {
        short8 vf = *(const short8*)&Vts[(n * 16 + lrow) * 64 +
                                         (((ks2 * 4 + lk8) ^ (lrow & 7))) * 8];
#pragma unroll
        for (int i = 0; i < 2; i++)
          acc[n][i] = __builtin_amdgcn_mfma_f32_16x16x32_bf16(vf, pf[i], acc[n][i], 0, 0, 0);
      }
    }
  }

  // ---- Epilogue: normalize, store O [s][h*128+d] ----
#pragma unroll
  for (int i = 0; i < 2; i++) {
    float inv = 1.0f / l_i[i];
    int row = qi * 128 + w * 32 + i * 16 + lrow;
#pragma unroll
    for (int n = 0; n < 8; n++) {
      ushort4 o;
      o.x = f2bf(acc[n][i][0] * inv); o.y = f2bf(acc[n][i][1] * inv);
      o.z = f2bf(acc[n][i][2] * inv); o.w = f2bf(acc[n][i][3] * inv);
      *(ushort4*)&Ob[(size_t)row * 4096 + h * 128 + n * 16 + lk8 * 4] = o;
    }
  }
}

// ---------------------------------------------------------------------------
extern "C" void kernel_launch(void* const* d_in, const int* in_sizes, int n_in,
                              void* d_out, int out_size, void* d_ws, size_t ws_size,
                              hipStream_t stream) {
  const float* X  = (const float*)d_in[0];
  const float* Wq = (const float*)d_in[1];
  const float* Wk = (const float*)d_in[2];
  const float* Wv = (const float*)d_in[3];
  const float* Wo = (const float*)d_in[4];
  float* out = (float*)d_out;

  char* p = (char*)d_ws;
  unsigned short* Qb  = (unsigned short*)p; p += (size_t)S_LEN * 4096 * 2;  // 16.8 MB
  unsigned short* Kb  = (unsigned short*)p; p += (size_t)S_LEN * 1024 * 2;  //  4.2 MB
  unsigned short* Vb  = (unsigned short*)p; p += (size_t)S_LEN * 1024 * 2;  //  4.2 MB
  unsigned short* Qp  = (unsigned short*)p; p += (size_t)S_LEN * 4096 * 2;  // 16.8 MB
  unsigned short* Kp  = (unsigned short*)p; p += (size_t)S_LEN * 1024 * 2;  //  4.2 MB
  unsigned short* Vp  = (unsigned short*)p; p += (size_t)S_LEN * 1024 * 2;  //  4.2 MB
  unsigned short* Xb  = (unsigned short*)p; p += (size_t)S_LEN * 4096 * 2;  // 16.8 MB
  unsigned short* Wqb = (unsigned short*)p; p += (size_t)4096 * 4096 * 2;   // 33.6 MB
  unsigned short* Wkb = (unsigned short*)p; p += (size_t)1024 * 4096 * 2;   //  8.4 MB
  unsigned short* Wvb = (unsigned short*)p; p += (size_t)1024 * 4096 * 2;   //  8.4 MB
  unsigned short* Ob  = Xb;   // Xb dead after gemm_qkv
  unsigned short* Wob = Wqb;  // Wqb dead after gemm_qkv

  // 1. fp32 -> bf16
  conv_bf16<<<(S_LEN * 4096 / 4 + 255) / 256, 256, 0, stream>>>(X, Xb, S_LEN * 4096);
  conv_bf16<<<(4096 * 4096 / 4 + 255) / 256, 256, 0, stream>>>(Wq, Wqb, 4096 * 4096);
  conv_bf16<<<(1024 * 4096 / 4 + 255) / 256, 256, 0, stream>>>(Wk, Wkb, 1024 * 4096);
  conv_bf16<<<(1024 * 4096 / 4 + 255) / 256, 256, 0, stream>>>(Wv, Wvb, 1024 * 4096);

  // 2. Fused QKV projection -> bf16
  gemm_qkv<<<dim3(6144 / 128, S_LEN / 128), 256, 0, stream>>>(Xb, Wqb, Wkb, Wvb, Qb, Kb, Vb);

  // 3. RoPE -> packed Qp/Kp tile layouts (Q pre-scaled into exp2 domain)
  int rope_threads = S_LEN * (N_HEADS + N_KV) * 64;
  rope_kernel<<<rope_threads / 256, 256, 0, stream>>>(Qb, Kb, Qp, Kp);

  // 4. V transpose -> packed Vp tiles
  transp_v<<<dim3(S_LEN / 64, 1024 / 64), 256, 0, stream>>>(Vb, Vp);

  // 5. Convert Wo (into Wqb space)
  conv_bf16<<<(4096 * 4096 / 4 + 255) / 256, 256, 0, stream>>>(Wo, Wob, 4096 * 4096);

  // 6. MFMA flash attention v4 -> bf16 (into Xb space)
  attn_mfma<<<512, 256, 0, stream>>>(Qp, Kp, Vp, Ob);

  // 7. Output projection
  gemm_out<<<dim3(4096 / 128, S_LEN / 128), 256, 0, stream>>>(Ob, Wob, out);
}

// Round 3
// 507.512 us; speedup vs baseline: 1.1393x; 1.1393x over previous
//
#include <hip/hip_runtime.h>
#include <hip/hip_bf16.h>
#include <math.h>

// Problem constants
#define S_LEN 2048
#define HIDDEN 4096
#define N_HEADS 32
#define N_KV 8
#define HEAD_DIM 128

typedef __attribute__((ext_vector_type(8))) short short8;   // 8 bf16 = 4 VGPRs
typedef __attribute__((ext_vector_type(4))) float f32x4;    // MFMA C/D frag

typedef __attribute__((address_space(3))) unsigned int as3_u32;
typedef const __attribute__((address_space(1))) unsigned int as1_u32;

__device__ __forceinline__ void gload16(const void* g, void* lds) {
  __builtin_amdgcn_global_load_lds((as1_u32*)g, (as3_u32*)lds, 16, 0, 0);
}

__device__ __forceinline__ unsigned short f2bf(float f) {
  unsigned int u = __float_as_uint(f);
  return (unsigned short)((u + 0x7fff + ((u >> 16) & 1)) >> 16);  // RNE
}
__device__ __forceinline__ float bf2f(unsigned short u) {
  return __uint_as_float(((unsigned int)u) << 16);
}

// ---------------------------------------------------------------------------
// fp32 -> bf16 conversion, 4 elems/thread
// ---------------------------------------------------------------------------
__global__ void conv_bf16(const float* __restrict__ in, unsigned short* __restrict__ out, int n) {
  int i = (blockIdx.x * blockDim.x + threadIdx.x) * 4;
  if (i >= n) return;
  float4 v = *(const float4*)&in[i];
  ushort4 o;
  o.x = f2bf(v.x); o.y = f2bf(v.y); o.z = f2bf(v.z); o.w = f2bf(v.w);
  *(ushort4*)&out[i] = o;
}

// ---------------------------------------------------------------------------
// m97-style bf16 MFMA GEMM core: one 128x128 C-tile per 256-thread block.
// ---------------------------------------------------------------------------
__device__ __forceinline__ void storeC(float* C, float v) { *C = v; }
__device__ __forceinline__ void storeC(unsigned short* C, float v) { *C = f2bf(v); }

template <typename OutT>
__device__ __forceinline__ void gemm_core_128(
    const unsigned short* __restrict__ A, const unsigned short* __restrict__ B,
    OutT* __restrict__ C, int K, int ldc) {
  __shared__ unsigned short As[128 * 32];
  __shared__ unsigned short Bs[128 * 32];

  const int tid = threadIdx.x;
  const int w = tid >> 6;
  const int lane = tid & 63;
  const int wr = (w >> 1) * 64;
  const int wc = (w & 1) * 64;
  const int lrow = lane & 15;
  const int lk8 = lane >> 4;

  f32x4 acc[4][4];
#pragma unroll
  for (int i = 0; i < 4; i++)
#pragma unroll
    for (int j = 0; j < 4; j++) acc[i][j] = (f32x4){0.f, 0.f, 0.f, 0.f};

  const int sr = (lane >> 2);
  const int sc = (lane & 3) * 8;

  for (int k0 = 0; k0 < K; k0 += 32) {
    __syncthreads();
#pragma unroll
    for (int s = 0; s < 2; s++) {
      int r = w * 32 + s * 16 + sr;
      gload16(&A[(size_t)r * K + k0 + sc], &As[(w * 32 + s * 16) * 32]);
      gload16(&B[(size_t)r * K + k0 + sc], &Bs[(w * 32 + s * 16) * 32]);
    }
    __syncthreads();

    short8 a[4], b[4];
#pragma unroll
    for (int i = 0; i < 4; i++)
      a[i] = *(const short8*)&As[(wr + i * 16 + lrow) * 32 + lk8 * 8];
#pragma unroll
    for (int j = 0; j < 4; j++)
      b[j] = *(const short8*)&Bs[(wc + j * 16 + lrow) * 32 + lk8 * 8];
#pragma unroll
    for (int i = 0; i < 4; i++)
#pragma unroll
      for (int j = 0; j < 4; j++)
        acc[i][j] = __builtin_amdgcn_mfma_f32_16x16x32_bf16(a[i], b[j], acc[i][j], 0, 0, 0);
  }

#pragma unroll
  for (int i = 0; i < 4; i++)
#pragma unroll
    for (int j = 0; j < 4; j++) {
      int col = wc + j * 16 + lrow;
#pragma unroll
      for (int r = 0; r < 4; r++) {
        int row = wr + i * 16 + lk8 * 4 + r;
        storeC(&C[(size_t)row * ldc + col], acc[i][j][r]);
      }
    }
}

// Fused QKV projection -> bf16 outputs Qb [S,4096], Kb [S,1024], Vb [S,1024]
__global__ __launch_bounds__(256) void gemm_qkv(
    const unsigned short* __restrict__ Xb,
    const unsigned short* __restrict__ Wqb, const unsigned short* __restrict__ Wkb,
    const unsigned short* __restrict__ Wvb,
    unsigned short* __restrict__ Qb, unsigned short* __restrict__ Kb,
    unsigned short* __restrict__ Vb) {
  const int colBase = blockIdx.x * 128;
  const int rowBase = blockIdx.y * 128;
  const unsigned short* B;
  unsigned short* C;
  int ldc, ccol;
  if (colBase < 4096)      { B = Wqb + (size_t)colBase * HIDDEN;          C = Qb; ldc = 4096; ccol = colBase; }
  else if (colBase < 5120) { B = Wkb + (size_t)(colBase - 4096) * HIDDEN; C = Kb; ldc = 1024; ccol = colBase - 4096; }
  else                     { B = Wvb + (size_t)(colBase - 5120) * HIDDEN; C = Vb; ldc = 1024; ccol = colBase - 5120; }
  gemm_core_128(Xb + (size_t)rowBase * HIDDEN, B,
                C + (size_t)rowBase * ldc + ccol, HIDDEN, ldc);
}

// Output projection: [2048,4096](bf16) @ Wo^T -> fp32 out
__global__ __launch_bounds__(256) void gemm_out(
    const unsigned short* __restrict__ Ob, const unsigned short* __restrict__ Wob,
    float* __restrict__ C) {
  const int colBase = blockIdx.x * 128;
  const int rowBase = blockIdx.y * 128;
  gemm_core_128(Ob + (size_t)rowBase * HIDDEN, Wob + (size_t)colBase * HIDDEN,
                C + (size_t)rowBase * HIDDEN + colBase, HIDDEN, HIDDEN);
}

// ---------------------------------------------------------------------------
// RoPE on bf16 Q/K, writing PACKED tile layouts:
//   Qp: per (head, 16-query strip) contiguous 4 KB:
//       Qp[((h*128 + (s>>4))*16 + (s&15))*128 + d]
//   Kp: per (kv head, 64-key tile) contiguous 16 KB:
//       Kp[((kvh*32 + (s>>6))*64 + (s&63))*128 + d]
// Q additionally scaled by 1/sqrt(128) * log2(e)  (exp2-domain softmax).
// ---------------------------------------------------------------------------
#define QSCALE 0.12753102123752056f  // 0.08838834764831845 * 1.4426950408889634

__global__ void rope_kernel(const unsigned short* __restrict__ Q,
                            const unsigned short* __restrict__ K,
                            unsigned short* __restrict__ Qp,
                            unsigned short* __restrict__ Kp) {
  int idx = blockIdx.x * blockDim.x + threadIdx.x;
  int d = idx & 63;
  int sh = idx >> 6;
  int h = sh % (N_HEADS + N_KV);
  int s = sh / (N_HEADS + N_KV);
  if (s >= S_LEN) return;

  float freq = expf(-(float)d * (9.210340371976184f / 64.0f));
  float ang = (float)s * freq;
  float sn, cs;
  sincosf(ang, &sn, &cs);

  const unsigned short* src;
  unsigned short* dst;
  float sc_out;
  if (h < N_HEADS) {
    src = Q + ((size_t)s * N_HEADS + h) * HEAD_DIM;
    dst = Qp + (((size_t)h * 128 + (s >> 4)) * 16 + (s & 15)) * HEAD_DIM;
    sc_out = QSCALE;
  } else {
    int kvh = h - N_HEADS;
    src = K + ((size_t)s * N_KV + kvh) * HEAD_DIM;
    dst = Kp + (((size_t)kvh * 32 + (s >> 6)) * 64 + (s & 63)) * HEAD_DIM;
    sc_out = 1.0f;
  }

  float x1 = bf2f(src[d]);
  float x2 = bf2f(src[d + 64]);
  dst[d] = f2bf((x1 * cs - x2 * sn) * sc_out);
  dst[d + 64] = f2bf((x2 * cs + x1 * sn) * sc_out);
}

// ---------------------------------------------------------------------------
// V transpose into PACKED tiles: Vb [S,1024] -> Vp, per (kvh, 64-key tile)
// contiguous 16 KB of [128 dims][64 keys]:
//   Vp[((kvh*32 + kt)*128 + d)*64 + k]
// ---------------------------------------------------------------------------
__global__ __launch_bounds__(256) void transp_v(
    const unsigned short* __restrict__ Vb, unsigned short* __restrict__ Vp) {
  __shared__ unsigned short t[64][72];
  const int s0 = blockIdx.x * 64;   // key tile base
  const int c0 = blockIdx.y * 64;   // flat dim base (kvh*128 + d)
  const int kt = s0 >> 6;
  const int tid = threadIdx.x;
#pragma unroll
  for (int i = 0; i < 2; i++) {
    int c = tid + i * 256;
    int r = c >> 3, ch = c & 7;
    *(short8*)&t[r][ch * 8] = *(const short8*)&Vb[(size_t)(s0 + r) * 1024 + c0 + ch * 8];
  }
  __syncthreads();
#pragma unroll
  for (int i = 0; i < 4; i++) {
    int c = tid + i * 256;
    int orow = c >> 4, oc4 = (c & 15) * 4;
    int g = c0 + orow;               // flat dim
    int kvh = g >> 7, d = g & 127;
    ushort4 o;
    o.x = t[oc4 + 0][orow]; o.y = t[oc4 + 1][orow];
    o.z = t[oc4 + 2][orow]; o.w = t[oc4 + 3][orow];
    *(ushort4*)&Vp[(((size_t)kvh * 32 + kt) * 128 + d) * 64 + oc4] = o;
  }
}

// ---------------------------------------------------------------------------
// MFMA flash attention v5: occupancy-doubled variant of v4.
// Block = 64 queries x 1 head, 4 waves x 16 queries. K-tiles of 64.
// Grid 1024 (32 heads x 32 q-tiles) -> 4 blocks/CU (LDS 40 KB), 16 waves/CU
// (was 2 blocks/CU, 8 waves/CU at 128-query tiles -> latency-bound, MfmaUtil
// 9.5%). Staging bytes double but stay <<L2 ceiling; MFMA count unchanged.
// K (64x128) and V^T (128x64) staged per tile via global_load_lds width=16
// from contiguous 16 KB buffers with XOR swizzle baked into the per-lane
// SOURCE address (LDS dest must stay lane-contiguous).
//   K LDS:  chunk (row r, pos p) holds global chunk (r, p ^ (r&15))
//   Vt LDS: chunk (row r, pos p) holds global chunk (r, p ^ (r&7))
// P buffer: wave-private 16x64, 16B-granular XOR swizzle (c16 ^= row&7) so
// rows (stride 128 B) don't collide and short8 reads stay contiguous.
// Blocks b and b+512 get q-tiles j and 31-j: 33 tiles combined (balanced).
// ---------------------------------------------------------------------------
#define AK 64

__global__ __launch_bounds__(256, 4) void attn_mfma(
    const unsigned short* __restrict__ Qp, const unsigned short* __restrict__ Kp,
    const unsigned short* __restrict__ Vp, unsigned short* __restrict__ Ob) {
  const int b = blockIdx.x;
  const int h = b & 31;
  const int j = b >> 5;
  const int qt = (b < 512) ? j : (47 - j);   // 0..31, paired for balance
  const int kvh = h >> 2;

  const int tid = threadIdx.x;
  const int w = tid >> 6;
  const int lane = tid & 63;
  const int lrow = lane & 15;
  const int lk8 = lane >> 4;

  __shared__ unsigned short Ks[64 * 128];    // 16 KB, swizzled
  __shared__ unsigned short Vts[128 * 64];   // 16 KB, swizzled
  __shared__ unsigned short Ps[4 * 16 * 64]; // 8 KB, wave-private, swizzled
  unsigned short* Pw = &Ps[w * 16 * 64];

  // ---- Q fragments: wave w owns query strip qt*64 + w*16 .. +15 ----
  short8 qf[4];
  const int t0 = qt * 4 + w;                 // packed 16-query strip index
#pragma unroll
  for (int ks = 0; ks < 4; ks++)
    qf[ks] = *(const short8*)&Qp[(((size_t)h * 128 + t0) * 16 + lrow) * 128 +
                                 ks * 32 + lk8 * 8];

  f32x4 acc[8];  // O^T: [dim-tile], queries = lane&15
  float m_i = -1e30f, l_i = 0.f;
#pragma unroll
  for (int n = 0; n < 8; n++) acc[n] = (f32x4){0.f, 0.f, 0.f, 0.f};

  const int nkt = qt + 1;

  for (int kt = 0; kt < nkt; kt++) {
    const int kb = kt * AK;
    const unsigned short* Kt  = Kp + ((size_t)kvh * 32 + kt) * 8192;
    const unsigned short* Vtt = Vp + ((size_t)kvh * 32 + kt) * 8192;

    __syncthreads();  // all waves done reading previous tile
    // ---- Stage K + V^T (16 KB each) with swizzled contiguous sources ----
#pragma unroll
    for (int jj = 0; jj < 4; jj++) {
      int seg = w * 4 + jj;                 // 0..15, 1 KB LDS segment
      // K: lds slot (r = seg*4 + lk8, p = lrow) <- global chunk (r, p^(r&15))
      int kr = seg * 4 + lk8;
      int kc = lrow ^ (kr & 15);
      gload16(Kt + ((size_t)kr * 16 + kc) * 8, &Ks[seg * 512]);
      // Vt: lds slot (r = seg*8 + lane>>3, p = lane&7) <- chunk (r, p^(r&7))
      int vr = seg * 8 + (lane >> 3);
      int vc = (lane & 7) ^ (vr & 7);
      gload16(Vtt + ((size_t)vr * 8 + vc) * 8, &Vts[seg * 512]);
    }
    __syncthreads();  // barrier drains vmcnt -> staged data visible

    // ---- S^T = K Q^T ----
    f32x4 s[4];
#pragma unroll
    for (int n = 0; n < 4; n++) s[n] = (f32x4){0.f, 0.f, 0.f, 0.f};

#pragma unroll
    for (int ks = 0; ks < 4; ks++) {
      short8 kf[4];
#pragma unroll
      for (int n = 0; n < 4; n++)
        kf[n] = *(const short8*)&Ks[(n * 16 + lrow) * 128 + (((ks * 4 + lk8) ^ lrow)) * 8];
#pragma unroll
      for (int n = 0; n < 4; n++)
        s[n] = __builtin_amdgcn_mfma_f32_16x16x32_bf16(kf[n], qf[ks], s[n], 0, 0, 0);
    }

    // ---- Causal mask: rows=keys (lk8*4+r), cols=queries (lrow) ----
    const int wqb = qt * 64 + w * 16;
    if (kb + AK - 1 > wqb) {
      int query = wqb + lrow;
#pragma unroll
      for (int n = 0; n < 4; n++) {
        int keyb = kb + n * 16 + lk8 * 4;
#pragma unroll
        for (int r = 0; r < 4; r++)
          if (keyb + r > query) s[n][r] = -1e30f;
      }
    }

    // ---- Online softmax (exp2): 16 in-lane scores + 2 shuffles ----
    {
      float mx = -1e30f;
#pragma unroll
      for (int n = 0; n < 4; n++)
#pragma unroll
        for (int r = 0; r < 4; r++) mx = fmaxf(mx, s[n][r]);
      mx = fmaxf(mx, __shfl_xor(mx, 16, 64));
      mx = fmaxf(mx, __shfl_xor(mx, 32, 64));
      float mn = fmaxf(m_i, mx);
      float al = exp2f(m_i - mn);
      m_i = mn;
      float ls = 0.f;
#pragma unroll
      for (int n = 0; n < 4; n++)
#pragma unroll
        for (int r = 0; r < 4; r++) {
          float e = exp2f(s[n][r] - mn);
          s[n][r] = e;
          ls += e;
        }
      ls += __shfl_xor(ls, 16, 64);
      ls += __shfl_xor(ls, 32, 64);
      l_i = l_i * al + ls;
#pragma unroll
      for (int n = 0; n < 8; n++)
#pragma unroll
        for (int r = 0; r < 4; r++) acc[n][r] *= al;
    }

    // ---- P -> wave-private LDS [query][key], 16B-granular XOR swizzle ----
#pragma unroll
    for (int n = 0; n < 4; n++) {
      ushort4 pk;
      pk.x = f2bf(s[n][0]); pk.y = f2bf(s[n][1]);
      pk.z = f2bf(s[n][2]); pk.w = f2bf(s[n][3]);
      int c8 = n * 4 + lk8;                      // 8B chunk 0..15 in row
      int c16s = (c8 >> 1) ^ (lrow & 7);         // swizzled 16B slot
      *(ushort4*)&Pw[lrow * 64 + c16s * 8 + (c8 & 1) * 4] = pk;
    }

    // ---- O^T += V^T P^T ----
#pragma unroll
    for (int ks2 = 0; ks2 < 2; ks2++) {
      int c16s = (ks2 * 4 + lk8) ^ (lrow & 7);
      short8 pf = *(const short8*)&Pw[lrow * 64 + c16s * 8];
#pragma unroll
      for (int n = 0; n < 8; n++) {
        short8 vf = *(const short8*)&Vts[(n * 16 + lrow) * 64 +
                                         (((ks2 * 4 + lk8) ^ (lrow & 7))) * 8];
        acc[n] = __builtin_amdgcn_mfma_f32_16x16x32_bf16(vf, pf, acc[n], 0, 0, 0);
      }
    }
  }

  // ---- Epilogue: normalize, store O [s][h*128+d] ----
  {
    float inv = 1.0f / l_i;
    int row = qt * 64 + w * 16 + lrow;
#pragma unroll
    for (int n = 0; n < 8; n++) {
      ushort4 o;
      o.x = f2bf(acc[n][0] * inv); o.y = f2bf(acc[n][1] * inv);
      o.z = f2bf(acc[n][2] * inv); o.w = f2bf(acc[n][3] * inv);
      *(ushort4*)&Ob[(size_t)row * 4096 + h * 128 + n * 16 + lk8 * 4] = o;
    }
  }
}

// ---------------------------------------------------------------------------
extern "C" void kernel_launch(void* const* d_in, const int* in_sizes, int n_in,
                              void* d_out, int out_size, void* d_ws, size_t ws_size,
                              hipStream_t stream) {
  const float* X  = (const float*)d_in[0];
  const float* Wq = (const float*)d_in[1];
  const float* Wk = (const float*)d_in[2];
  const float* Wv = (const float*)d_in[3];
  const float* Wo = (const float*)d_in[4];
  float* out = (float*)d_out;

  char* p = (char*)d_ws;
  unsigned short* Qb  = (unsigned short*)p; p += (size_t)S_LEN * 4096 * 2;  // 16.8 MB
  unsigned short* Kb  = (unsigned short*)p; p += (size_t)S_LEN * 1024 * 2;  //  4.2 MB
  unsigned short* Vb  = (unsigned short*)p; p += (size_t)S_LEN * 1024 * 2;  //  4.2 MB
  unsigned short* Qp  = (unsigned short*)p; p += (size_t)S_LEN * 4096 * 2;  // 16.8 MB
  unsigned short* Kp  = (unsigned short*)p; p += (size_t)S_LEN * 1024 * 2;  //  4.2 MB
  unsigned short* Vp  = (unsigned short*)p; p += (size_t)S_LEN * 1024 * 2;  //  4.2 MB
  unsigned short* Xb  = (unsigned short*)p; p += (size_t)S_LEN * 4096 * 2;  // 16.8 MB
  unsigned short* Wqb = (unsigned short*)p; p += (size_t)4096 * 4096 * 2;   // 33.6 MB
  unsigned short* Wkb = (unsigned short*)p; p += (size_t)1024 * 4096 * 2;   //  8.4 MB
  unsigned short* Wvb = (unsigned short*)p; p += (size_t)1024 * 4096 * 2;   //  8.4 MB
  unsigned short* Ob  = Xb;   // Xb dead after gemm_qkv
  unsigned short* Wob = Wqb;  // Wqb dead after gemm_qkv

  // 1. fp32 -> bf16
  conv_bf16<<<(S_LEN * 4096 / 4 + 255) / 256, 256, 0, stream>>>(X, Xb, S_LEN * 4096);
  conv_bf16<<<(4096 * 4096 / 4 + 255) / 256, 256, 0, stream>>>(Wq, Wqb, 4096 * 4096);
  conv_bf16<<<(1024 * 4096 / 4 + 255) / 256, 256, 0, stream>>>(Wk, Wkb, 1024 * 4096);
  conv_bf16<<<(1024 * 4096 / 4 + 255) / 256, 256, 0, stream>>>(Wv, Wvb, 1024 * 4096);

  // 2. Fused QKV projection -> bf16
  gemm_qkv<<<dim3(6144 / 128, S_LEN / 128), 256, 0, stream>>>(Xb, Wqb, Wkb, Wvb, Qb, Kb, Vb);

  // 3. RoPE -> packed Qp/Kp tile layouts (Q pre-scaled into exp2 domain)
  int rope_threads = S_LEN * (N_HEADS + N_KV) * 64;
  rope_kernel<<<rope_threads / 256, 256, 0, stream>>>(Qb, Kb, Qp, Kp);

  // 4. V transpose -> packed Vp tiles
  transp_v<<<dim3(S_LEN / 64, 1024 / 64), 256, 0, stream>>>(Vb, Vp);

  // 5. Convert Wo (into Wqb space)
  conv_bf16<<<(4096 * 4096 / 4 + 255) / 256, 256, 0, stream>>>(Wo, Wob, 4096 * 4096);

  // 6. MFMA flash attention v5 -> bf16 (into Xb space), 64-query blocks
  attn_mfma<<<1024, 256, 0, stream>>>(Qp, Kp, Vp, Ob);

  // 7. Output projection
  gemm_out<<<dim3(4096 / 128, S_LEN / 128), 256, 0, stream>>>(Ob, Wob, out);
}

// Round 4
// 493.447 us; speedup vs baseline: 1.1718x; 1.0285x over previous
//
#include <hip/hip_runtime.h>
#include <hip/hip_bf16.h>
#include <math.h>

// Problem constants
#define S_LEN 2048
#define HIDDEN 4096
#define N_HEADS 32
#define N_KV 8
#define HEAD_DIM 128

typedef __attribute__((ext_vector_type(8))) short short8;   // 8 bf16 = 4 VGPRs
typedef __attribute__((ext_vector_type(4))) float f32x4;    // MFMA C/D frag

typedef __attribute__((address_space(3))) unsigned int as3_u32;
typedef const __attribute__((address_space(1))) unsigned int as1_u32;

__device__ __forceinline__ void gload16(const void* g, void* lds) {
  __builtin_amdgcn_global_load_lds((as1_u32*)g, (as3_u32*)lds, 16, 0, 0);
}

__device__ __forceinline__ unsigned short f2bf(float f) {
  unsigned int u = __float_as_uint(f);
  return (unsigned short)((u + 0x7fff + ((u >> 16) & 1)) >> 16);  // RNE
}
__device__ __forceinline__ float bf2f(unsigned short u) {
  return __uint_as_float(((unsigned int)u) << 16);
}

// ---------------------------------------------------------------------------
// fp32 -> bf16 conversion, 4 elems/thread
// ---------------------------------------------------------------------------
__global__ void conv_bf16(const float* __restrict__ in, unsigned short* __restrict__ out, int n) {
  int i = (blockIdx.x * blockDim.x + threadIdx.x) * 4;
  if (i >= n) return;
  float4 v = *(const float4*)&in[i];
  ushort4 o;
  o.x = f2bf(v.x); o.y = f2bf(v.y); o.z = f2bf(v.z); o.w = f2bf(v.w);
  *(ushort4*)&out[i] = o;
}

__device__ __forceinline__ void storeC(float* C, float v) { *C = v; }
__device__ __forceinline__ void storeC(unsigned short* C, float v) { *C = f2bf(v); }

// ---------------------------------------------------------------------------
// 8-phase-style bf16 MFMA GEMM core (T3+T4+T5 port):
//   256x128 C-tile per 512-thread block (8 waves as 4Mx2N, 64x64 per wave).
//   BK=64 K-tiles, TRIPLE-buffered LDS (3 x 48 KB = 144 KB): compute tile t
//   from buf[t%3] while staging tile t+2 into buf[(t+2)%3] -> staging writes
//   never touch a buffer being read (removes half-tile aliasing hazard).
//   Counted s_waitcnt vmcnt(6) once per K-tile (6 gloads/tile/wave in
//   flight across barriers); vmcnt(0) only at the pipeline tail.
//   2 phases per K-tile: {ds_read batch | 3 gloads | s_barrier | 16 MFMA
//   in setprio(1)}; b-frags read once in phase A, reused in phase B.
//   LDS XOR swizzle via per-lane SOURCE address (16B chunk p <- p^(r&7)),
//   reads use matching XOR -> 16-way bank conflict becomes 2-way (free).
//   FP accumulation order per output element identical to the old core
//   (k = 0,32,64,... sequential).
// ---------------------------------------------------------------------------
#define BM 256
#define BN 128
#define BK 64
#define NKT (HIDDEN / BK)   // 64 K-tiles

template <typename OutT>
__device__ __forceinline__ void gemm_core_256x128(
    const unsigned short* __restrict__ A,   // row-major [*][4096], pre-offset to rowBase
    const unsigned short* __restrict__ B,   // row-major [*][4096], pre-offset to colBase
    OutT* __restrict__ C, int ldc) {
  __shared__ unsigned short Abuf[3][BM * BK];   // 3 x 32 KB
  __shared__ unsigned short Bbuf[3][BN * BK];   // 3 x 16 KB

  const int tid = threadIdx.x;
  const int w = tid >> 6;          // 0..7
  const int lane = tid & 63;
  const int lrow = lane & 15;
  const int lk8 = lane >> 4;       // 0..3
  const int wr = (w >> 1) * 64;    // wave M base: 0,64,128,192
  const int wc = (w & 1) * 64;     // wave N base: 0,64
  const int lr8 = lane >> 3;       // staging: row within 8-row segment
  const int lp = lane & 7;         // staging: chunk position 0..7

  f32x4 acc[4][4];
#pragma unroll
  for (int i = 0; i < 4; i++)
#pragma unroll
    for (int j = 0; j < 4; j++) acc[i][j] = (f32x4){0.f, 0.f, 0.f, 0.f};

  // Stage one 1 KB segment (8 rows x 8 chunks): LDS linear, source swizzled.
  // Lane l covers LDS chunk seg*64 + l -> (r = seg*8 + l>>3, p = l&7), whose
  // content is global chunk (r, p ^ (r&7)).
#define STAGE_A(bi, t, g) {                                                  \
    int seg = (g) * 8 + w;                                                   \
    int r = seg * 8 + lr8;                                                   \
    int c = lp ^ (r & 7);                                                    \
    gload16(&A[(size_t)r * HIDDEN + (t) * BK + c * 8], &Abuf[bi][seg * 512]);\
  }
#define STAGE_B(bi, t, g) {                                                  \
    int seg = (g) * 8 + w;                                                   \
    int r = seg * 8 + lr8;                                                   \
    int c = lp ^ (r & 7);                                                    \
    gload16(&B[(size_t)r * HIDDEN + (t) * BK + c * 8], &Bbuf[bi][seg * 512]);\
  }
  // Fragment read: global chunk (r, ks*4+lk8) lives at p = (ks*4+lk8)^(r&7).
#define RD_FRAG(buf, rbase, ks)                                              \
  (*(const short8*)&(buf)[((rbase) + lrow) * 64 + (((ks) * 4 + lk8) ^ (((rbase) + lrow) & 7)) * 8])

  // ---- prologue: stage tiles 0 and 1 ----
#pragma unroll
  for (int g = 0; g < 4; g++) STAGE_A(0, 0, g);
#pragma unroll
  for (int g = 0; g < 2; g++) STAGE_B(0, 0, g);
#pragma unroll
  for (int g = 0; g < 4; g++) STAGE_A(1, 1, g);
#pragma unroll
  for (int g = 0; g < 2; g++) STAGE_B(1, 1, g);
  asm volatile("s_waitcnt vmcnt(6)" ::: "memory");  // tile0 resident
  __builtin_amdgcn_s_barrier();

  for (int t = 0; t < NKT; t++) {
    const int bi = t % 3;
    const int bs = (t + 2) % 3;
    const bool st = (t + 2) < NKT;
    const unsigned short* Ac = Abuf[bi];
    const unsigned short* Bc = Bbuf[bi];

    short8 bfr[4][2], afr[2][2];

    // ---- phase A: 12 ds_read | 3 gloads | barrier | 16 MFMA (m=0,1) ----
#pragma unroll
    for (int n = 0; n < 4; n++)
#pragma unroll
      for (int ks = 0; ks < 2; ks++)
        bfr[n][ks] = RD_FRAG(Bc, wc + n * 16, ks);
#pragma unroll
    for (int m = 0; m < 2; m++)
#pragma unroll
      for (int ks = 0; ks < 2; ks++)
        afr[m][ks] = RD_FRAG(Ac, wr + m * 16, ks);
    if (st) { STAGE_A(bs, t + 2, 0); STAGE_A(bs, t + 2, 1); STAGE_B(bs, t + 2, 0); }
    __builtin_amdgcn_s_barrier();
    __builtin_amdgcn_s_setprio(1);
#pragma unroll
    for (int m = 0; m < 2; m++)
#pragma unroll
      for (int n = 0; n < 4; n++)
#pragma unroll
        for (int ks = 0; ks < 2; ks++)
          acc[m][n] = __builtin_amdgcn_mfma_f32_16x16x32_bf16(afr[m][ks], bfr[n][ks], acc[m][n], 0, 0, 0);
    __builtin_amdgcn_s_setprio(0);
    __builtin_amdgcn_s_barrier();

    // ---- phase B: 4 ds_read | 3 gloads | barrier | 16 MFMA (m=2,3) ----
#pragma unroll
    for (int m = 0; m < 2; m++)
#pragma unroll
      for (int ks = 0; ks < 2; ks++)
        afr[m][ks] = RD_FRAG(Ac, wr + (m + 2) * 16, ks);
    if (st) { STAGE_A(bs, t + 2, 2); STAGE_A(bs, t + 2, 3); STAGE_B(bs, t + 2, 1); }
    __builtin_amdgcn_s_barrier();
    __builtin_amdgcn_s_setprio(1);
#pragma unroll
    for (int m = 0; m < 2; m++)
#pragma unroll
      for (int n = 0; n < 4; n++)
#pragma unroll
        for (int ks = 0; ks < 2; ks++)
          acc[m + 2][n] = __builtin_amdgcn_mfma_f32_16x16x32_bf16(afr[m][ks], bfr[n][ks], acc[m + 2][n], 0, 0, 0);
    __builtin_amdgcn_s_setprio(0);
    // counted wait: tile t+1 (issued during iter t-1) must be resident for
    // next iter; up to 6 of tile t+2's loads may stay in flight.
    if (st) asm volatile("s_waitcnt vmcnt(6)" ::: "memory");
    else    asm volatile("s_waitcnt vmcnt(0)" ::: "memory");
    __builtin_amdgcn_s_barrier();
  }
#undef STAGE_A
#undef STAGE_B
#undef RD_FRAG

  // ---- epilogue: same C/D mapping as verified core ----
#pragma unroll
  for (int i = 0; i < 4; i++)
#pragma unroll
    for (int j = 0; j < 4; j++) {
      int col = wc + j * 16 + lrow;
#pragma unroll
      for (int r = 0; r < 4; r++) {
        int row = wr + i * 16 + lk8 * 4 + r;
        storeC(&C[(size_t)row * ldc + col], acc[i][j][r]);
      }
    }
}

// Fused QKV projection -> bf16 outputs Qb [S,4096], Kb [S,1024], Vb [S,1024]
// grid dim3(48, 8): col tiles of 128, row tiles of 256
__global__ __launch_bounds__(512, 2) void gemm_qkv(
    const unsigned short* __restrict__ Xb,
    const unsigned short* __restrict__ Wqb, const unsigned short* __restrict__ Wkb,
    const unsigned short* __restrict__ Wvb,
    unsigned short* __restrict__ Qb, unsigned short* __restrict__ Kb,
    unsigned short* __restrict__ Vb) {
  const int colBase = blockIdx.x * BN;
  const int rowBase = blockIdx.y * BM;
  const unsigned short* B;
  unsigned short* C;
  int ldc, ccol;
  if (colBase < 4096)      { B = Wqb + (size_t)colBase * HIDDEN;          C = Qb; ldc = 4096; ccol = colBase; }
  else if (colBase < 5120) { B = Wkb + (size_t)(colBase - 4096) * HIDDEN; C = Kb; ldc = 1024; ccol = colBase - 4096; }
  else                     { B = Wvb + (size_t)(colBase - 5120) * HIDDEN; C = Vb; ldc = 1024; ccol = colBase - 5120; }
  gemm_core_256x128(Xb + (size_t)rowBase * HIDDEN, B,
                    C + (size_t)rowBase * ldc + ccol, ldc);
}

// Output projection: [2048,4096](bf16) @ Wo^T -> fp32 out
// grid dim3(32, 8) = 256 blocks = exact CU fill
__global__ __launch_bounds__(512, 2) void gemm_out(
    const unsigned short* __restrict__ Ob, const unsigned short* __restrict__ Wob,
    float* __restrict__ C) {
  const int colBase = blockIdx.x * BN;
  const int rowBase = blockIdx.y * BM;
  gemm_core_256x128(Ob + (size_t)rowBase * HIDDEN, Wob + (size_t)colBase * HIDDEN,
                    C + (size_t)rowBase * HIDDEN + colBase, HIDDEN);
}

// ---------------------------------------------------------------------------
// RoPE on bf16 Q/K, writing PACKED tile layouts:
//   Qp: per (head, 16-query strip) contiguous 4 KB:
//       Qp[((h*128 + (s>>4))*16 + (s&15))*128 + d]
//   Kp: per (kv head, 64-key tile) contiguous 16 KB:
//       Kp[((kvh*32 + (s>>6))*64 + (s&63))*128 + d]
// Q additionally scaled by 1/sqrt(128) * log2(e)  (exp2-domain softmax).
// ---------------------------------------------------------------------------
#define QSCALE 0.12753102123752056f  // 0.08838834764831845 * 1.4426950408889634

__global__ void rope_kernel(const unsigned short* __restrict__ Q,
                            const unsigned short* __restrict__ K,
                            unsigned short* __restrict__ Qp,
                            unsigned short* __restrict__ Kp) {
  int idx = blockIdx.x * blockDim.x + threadIdx.x;
  int d = idx & 63;
  int sh = idx >> 6;
  int h = sh % (N_HEADS + N_KV);
  int s = sh / (N_HEADS + N_KV);
  if (s >= S_LEN) return;

  float freq = expf(-(float)d * (9.210340371976184f / 64.0f));
  float ang = (float)s * freq;
  float sn, cs;
  sincosf(ang, &sn, &cs);

  const unsigned short* src;
  unsigned short* dst;
  float sc_out;
  if (h < N_HEADS) {
    src = Q + ((size_t)s * N_HEADS + h) * HEAD_DIM;
    dst = Qp + (((size_t)h * 128 + (s >> 4)) * 16 + (s & 15)) * HEAD_DIM;
    sc_out = QSCALE;
  } else {
    int kvh = h - N_HEADS;
    src = K + ((size_t)s * N_KV + kvh) * HEAD_DIM;
    dst = Kp + (((size_t)kvh * 32 + (s >> 6)) * 64 + (s & 63)) * HEAD_DIM;
    sc_out = 1.0f;
  }

  float x1 = bf2f(src[d]);
  float x2 = bf2f(src[d + 64]);
  dst[d] = f2bf((x1 * cs - x2 * sn) * sc_out);
  dst[d + 64] = f2bf((x2 * cs + x1 * sn) * sc_out);
}

// ---------------------------------------------------------------------------
// V transpose into PACKED tiles: Vb [S,1024] -> Vp, per (kvh, 64-key tile)
// contiguous 16 KB of [128 dims][64 keys]:
//   Vp[((kvh*32 + kt)*128 + d)*64 + k]
// ---------------------------------------------------------------------------
__global__ __launch_bounds__(256) void transp_v(
    const unsigned short* __restrict__ Vb, unsigned short* __restrict__ Vp) {
  __shared__ unsigned short t[64][72];
  const int s0 = blockIdx.x * 64;   // key tile base
  const int c0 = blockIdx.y * 64;   // flat dim base (kvh*128 + d)
  const int kt = s0 >> 6;
  const int tid = threadIdx.x;
#pragma unroll
  for (int i = 0; i < 2; i++) {
    int c = tid + i * 256;
    int r = c >> 3, ch = c & 7;
    *(short8*)&t[r][ch * 8] = *(const short8*)&Vb[(size_t)(s0 + r) * 1024 + c0 + ch * 8];
  }
  __syncthreads();
#pragma unroll
  for (int i = 0; i < 4; i++) {
    int c = tid + i * 256;
    int orow = c >> 4, oc4 = (c & 15) * 4;
    int g = c0 + orow;               // flat dim
    int kvh = g >> 7, d = g & 127;
    ushort4 o;
    o.x = t[oc4 + 0][orow]; o.y = t[oc4 + 1][orow];
    o.z = t[oc4 + 2][orow]; o.w = t[oc4 + 3][orow];
    *(ushort4*)&Vp[(((size_t)kvh * 32 + kt) * 128 + d) * 64 + oc4] = o;
  }
}

// ---------------------------------------------------------------------------
// MFMA flash attention v5: occupancy-doubled (round-3 verified).
// Block = 64 queries x 1 head, 4 waves x 16 queries. K-tiles of 64.
// Grid 1024 -> 4 blocks/CU (LDS 40 KB), 16 waves/CU.
// ---------------------------------------------------------------------------
#define AK 64

__global__ __launch_bounds__(256, 4) void attn_mfma(
    const unsigned short* __restrict__ Qp, const unsigned short* __restrict__ Kp,
    const unsigned short* __restrict__ Vp, unsigned short* __restrict__ Ob) {
  const int b = blockIdx.x;
  const int h = b & 31;
  const int j = b >> 5;
  const int qt = (b < 512) ? j : (47 - j);   // 0..31, paired for balance
  const int kvh = h >> 2;

  const int tid = threadIdx.x;
  const int w = tid >> 6;
  const int lane = tid & 63;
  const int lrow = lane & 15;
  const int lk8 = lane >> 4;

  __shared__ unsigned short Ks[64 * 128];    // 16 KB, swizzled
  __shared__ unsigned short Vts[128 * 64];   // 16 KB, swizzled
  __shared__ unsigned short Ps[4 * 16 * 64]; // 8 KB, wave-private, swizzled
  unsigned short* Pw = &Ps[w * 16 * 64];

  // ---- Q fragments: wave w owns query strip qt*64 + w*16 .. +15 ----
  short8 qf[4];
  const int t0 = qt * 4 + w;                 // packed 16-query strip index
#pragma unroll
  for (int ks = 0; ks < 4; ks++)
    qf[ks] = *(const short8*)&Qp[(((size_t)h * 128 + t0) * 16 + lrow) * 128 +
                                 ks * 32 + lk8 * 8];

  f32x4 acc[8];  // O^T: [dim-tile], queries = lane&15
  float m_i = -1e30f, l_i = 0.f;
#pragma unroll
  for (int n = 0; n < 8; n++) acc[n] = (f32x4){0.f, 0.f, 0.f, 0.f};

  const int nkt = qt + 1;

  for (int kt = 0; kt < nkt; kt++) {
    const int kb = kt * AK;
    const unsigned short* Kt  = Kp + ((size_t)kvh * 32 + kt) * 8192;
    const unsigned short* Vtt = Vp + ((size_t)kvh * 32 + kt) * 8192;

    __syncthreads();  // all waves done reading previous tile
    // ---- Stage K + V^T (16 KB each) with swizzled contiguous sources ----
#pragma unroll
    for (int jj = 0; jj < 4; jj++) {
      int seg = w * 4 + jj;                 // 0..15, 1 KB LDS segment
      // K: lds slot (r = seg*4 + lk8, p = lrow) <- global chunk (r, p^(r&15))
      int kr = seg * 4 + lk8;
      int kc = lrow ^ (kr & 15);
      gload16(Kt + ((size_t)kr * 16 + kc) * 8, &Ks[seg * 512]);
      // Vt: lds slot (r = seg*8 + lane>>3, p = lane&7) <- chunk (r, p^(r&7))
      int vr = seg * 8 + (lane >> 3);
      int vc = (lane & 7) ^ (vr & 7);
      gload16(Vtt + ((size_t)vr * 8 + vc) * 8, &Vts[seg * 512]);
    }
    __syncthreads();  // barrier drains vmcnt -> staged data visible

    // ---- S^T = K Q^T ----
    f32x4 s[4];
#pragma unroll
    for (int n = 0; n < 4; n++) s[n] = (f32x4){0.f, 0.f, 0.f, 0.f};

#pragma unroll
    for (int ks = 0; ks < 4; ks++) {
      short8 kf[4];
#pragma unroll
      for (int n = 0; n < 4; n++)
        kf[n] = *(const short8*)&Ks[(n * 16 + lrow) * 128 + (((ks * 4 + lk8) ^ lrow)) * 8];
#pragma unroll
      for (int n = 0; n < 4; n++)
        s[n] = __builtin_amdgcn_mfma_f32_16x16x32_bf16(kf[n], qf[ks], s[n], 0, 0, 0);
    }

    // ---- Causal mask: rows=keys (lk8*4+r), cols=queries (lrow) ----
    const int wqb = qt * 64 + w * 16;
    if (kb + AK - 1 > wqb) {
      int query = wqb + lrow;
#pragma unroll
      for (int n = 0; n < 4; n++) {
        int keyb = kb + n * 16 + lk8 * 4;
#pragma unroll
        for (int r = 0; r < 4; r++)
          if (keyb + r > query) s[n][r] = -1e30f;
      }
    }

    // ---- Online softmax (exp2): 16 in-lane scores + 2 shuffles ----
    {
      float mx = -1e30f;
#pragma unroll
      for (int n = 0; n < 4; n++)
#pragma unroll
        for (int r = 0; r < 4; r++) mx = fmaxf(mx, s[n][r]);
      mx = fmaxf(mx, __shfl_xor(mx, 16, 64));
      mx = fmaxf(mx, __shfl_xor(mx, 32, 64));
      float mn = fmaxf(m_i, mx);
      float al = exp2f(m_i - mn);
      m_i = mn;
      float ls = 0.f;
#pragma unroll
      for (int n = 0; n < 4; n++)
#pragma unroll
        for (int r = 0; r < 4; r++) {
          float e = exp2f(s[n][r] - mn);
          s[n][r] = e;
          ls += e;
        }
      ls += __shfl_xor(ls, 16, 64);
      ls += __shfl_xor(ls, 32, 64);
      l_i = l_i * al + ls;
#pragma unroll
      for (int n = 0; n < 8; n++)
#pragma unroll
        for (int r = 0; r < 4; r++) acc[n][r] *= al;
    }

    // ---- P -> wave-private LDS [query][key], 16B-granular XOR swizzle ----
#pragma unroll
    for (int n = 0; n < 4; n++) {
      ushort4 pk;
      pk.x = f2bf(s[n][0]); pk.y = f2bf(s[n][1]);
      pk.z = f2bf(s[n][2]); pk.w = f2bf(s[n][3]);
      int c8 = n * 4 + lk8;                      // 8B chunk 0..15 in row
      int c16s = (c8 >> 1) ^ (lrow & 7);         // swizzled 16B slot
      *(ushort4*)&Pw[lrow * 64 + c16s * 8 + (c8 & 1) * 4] = pk;
    }

    // ---- O^T += V^T P^T ----
#pragma unroll
    for (int ks2 = 0; ks2 < 2; ks2++) {
      int c16s = (ks2 * 4 + lk8) ^ (lrow & 7);
      short8 pf = *(const short8*)&Pw[lrow * 64 + c16s * 8];
#pragma unroll
      for (int n = 0; n < 8; n++) {
        short8 vf = *(const short8*)&Vts[(n * 16 + lrow) * 64 +
                                         (((ks2 * 4 + lk8) ^ (lrow & 7))) * 8];
        acc[n] = __builtin_amdgcn_mfma_f32_16x16x32_bf16(vf, pf, acc[n], 0, 0, 0);
      }
    }
  }

  // ---- Epilogue: normalize, store O [s][h*128+d] ----
  {
    float inv = 1.0f / l_i;
    int row = qt * 64 + w * 16 + lrow;
#pragma unroll
    for (int n = 0; n < 8; n++) {
      ushort4 o;
      o.x = f2bf(acc[n][0] * inv); o.y = f2bf(acc[n][1] * inv);
      o.z = f2bf(acc[n][2] * inv); o.w = f2bf(acc[n][3] * inv);
      *(ushort4*)&Ob[(size_t)row * 4096 + h * 128 + n * 16 + lk8 * 4] = o;
    }
  }
}

// ---------------------------------------------------------------------------
extern "C" void kernel_launch(void* const* d_in, const int* in_sizes, int n_in,
                              void* d_out, int out_size, void* d_ws, size_t ws_size,
                              hipStream_t stream) {
  const float* X  = (const float*)d_in[0];
  const float* Wq = (const float*)d_in[1];
  const float* Wk = (const float*)d_in[2];
  const float* Wv = (const float*)d_in[3];
  const float* Wo = (const float*)d_in[4];
  float* out = (float*)d_out;

  char* p = (char*)d_ws;
  unsigned short* Qb  = (unsigned short*)p; p += (size_t)S_LEN * 4096 * 2;  // 16.8 MB
  unsigned short* Kb  = (unsigned short*)p; p += (size_t)S_LEN * 1024 * 2;  //  4.2 MB
  unsigned short* Vb  = (unsigned short*)p; p += (size_t)S_LEN * 1024 * 2;  //  4.2 MB
  unsigned short* Qp  = (unsigned short*)p; p += (size_t)S_LEN * 4096 * 2;  // 16.8 MB
  unsigned short* Kp  = (unsigned short*)p; p += (size_t)S_LEN * 1024 * 2;  //  4.2 MB
  unsigned short* Vp  = (unsigned short*)p; p += (size_t)S_LEN * 1024 * 2;  //  4.2 MB
  unsigned short* Xb  = (unsigned short*)p; p += (size_t)S_LEN * 4096 * 2;  // 16.8 MB
  unsigned short* Wqb = (unsigned short*)p; p += (size_t)4096 * 4096 * 2;   // 33.6 MB
  unsigned short* Wkb = (unsigned short*)p; p += (size_t)1024 * 4096 * 2;   //  8.4 MB
  unsigned short* Wvb = (unsigned short*)p; p += (size_t)1024 * 4096 * 2;   //  8.4 MB
  unsigned short* Ob  = Xb;   // Xb dead after gemm_qkv
  unsigned short* Wob = Wqb;  // Wqb dead after gemm_qkv

  // 1. fp32 -> bf16
  conv_bf16<<<(S_LEN * 4096 / 4 + 255) / 256, 256, 0, stream>>>(X, Xb, S_LEN * 4096);
  conv_bf16<<<(4096 * 4096 / 4 + 255) / 256, 256, 0, stream>>>(Wq, Wqb, 4096 * 4096);
  conv_bf16<<<(1024 * 4096 / 4 + 255) / 256, 256, 0, stream>>>(Wk, Wkb, 1024 * 4096);
  conv_bf16<<<(1024 * 4096 / 4 + 255) / 256, 256, 0, stream>>>(Wv, Wvb, 1024 * 4096);

  // 2. Fused QKV projection -> bf16 (256x128 tiles, 8-phase-style core)
  gemm_qkv<<<dim3(6144 / BN, S_LEN / BM), 512, 0, stream>>>(Xb, Wqb, Wkb, Wvb, Qb, Kb, Vb);

  // 3. RoPE -> packed Qp/Kp tile layouts (Q pre-scaled into exp2 domain)
  int rope_threads = S_LEN * (N_HEADS + N_KV) * 64;
  rope_kernel<<<rope_threads / 256, 256, 0, stream>>>(Qb, Kb, Qp, Kp);

  // 4. V transpose -> packed Vp tiles
  transp_v<<<dim3(S_LEN / 64, 1024 / 64), 256, 0, stream>>>(Vb, Vp);

  // 5. Convert Wo (into Wqb space)
  conv_bf16<<<(4096 * 4096 / 4 + 255) / 256, 256, 0, stream>>>(Wo, Wob, 4096 * 4096);

  // 6. MFMA flash attention v5 -> bf16 (into Xb space), 64-query blocks
  attn_mfma<<<1024, 256, 0, stream>>>(Qp, Kp, Vp, Ob);

  // 7. Output projection (256 blocks = exact CU fill)
  gemm_out<<<dim3(4096 / BN, S_LEN / BM), 512, 0, stream>>>(Ob, Wob, out);
}

// Round 5
// 475.266 us; speedup vs baseline: 1.2166x; 1.0383x over previous
//
#include <hip/hip_runtime.h>
#include <hip/hip_bf16.h>
#include <math.h>

// Problem constants
#define S_LEN 2048
#define HIDDEN 4096
#define N_HEADS 32
#define N_KV 8
#define HEAD_DIM 128

typedef __attribute__((ext_vector_type(8))) short short8;   // 8 bf16 = 4 VGPRs
typedef __attribute__((ext_vector_type(4))) float f32x4;    // MFMA C/D frag

typedef __attribute__((address_space(3))) unsigned int as3_u32;
typedef const __attribute__((address_space(1))) unsigned int as1_u32;

__device__ __forceinline__ void gload16(const void* g, void* lds) {
  __builtin_amdgcn_global_load_lds((as1_u32*)g, (as3_u32*)lds, 16, 0, 0);
}

__device__ __forceinline__ unsigned short f2bf(float f) {
  unsigned int u = __float_as_uint(f);
  return (unsigned short)((u + 0x7fff + ((u >> 16) & 1)) >> 16);  // RNE
}
__device__ __forceinline__ float bf2f(unsigned short u) {
  return __uint_as_float(((unsigned int)u) << 16);
}

// ---------------------------------------------------------------------------
// fp32 -> bf16 conversion, 4 elems/thread
// ---------------------------------------------------------------------------
__global__ void conv_bf16(const float* __restrict__ in, unsigned short* __restrict__ out, int n) {
  int i = (blockIdx.x * blockDim.x + threadIdx.x) * 4;
  if (i >= n) return;
  float4 v = *(const float4*)&in[i];
  ushort4 o;
  o.x = f2bf(v.x); o.y = f2bf(v.y); o.z = f2bf(v.z); o.w = f2bf(v.w);
  *(ushort4*)&out[i] = o;
}

__device__ __forceinline__ void storeC(float* C, float v) { *C = v; }
__device__ __forceinline__ void storeC(unsigned short* C, float v) { *C = f2bf(v); }

#define BM 256
#define BN 128

// ---------------------------------------------------------------------------
// Pipelined core v2 (gemm_qkv): 256x128 C-tile, 512 threads (8 waves 4Mx2N,
// 64x64 per wave), BK=32, TRIPLE-buffered LDS (3 x 24 KB = 72 KB) ->
// 2 blocks/CU co-resident (the round-4 regression root cause was 1 block/CU
// + a 1.5-round grid tail; 384 blocks now all co-resident, cross-block
// MFMA/LDS overlap). Stage tile t+2 while computing t (write buffer provably
// free: last read in iter t-1, sealed by two barriers). Counted vmcnt(3):
// 3 gloads/tile, FIFO retirement => t+1 resident, t+2 in flight.
// LDS rows are 64 B; source-swizzle chunk p <- p ^ (r&3), frag reads use the
// matching XOR (<=4-way residual conflict ~ free per m136).
// ---------------------------------------------------------------------------
#define BK2 32
#define NKT2 (HIDDEN / BK2)   // 128 K-tiles

__global__ __launch_bounds__(512, 4) void gemm_qkv(
    const unsigned short* __restrict__ Xb,
    const unsigned short* __restrict__ Wqb, const unsigned short* __restrict__ Wkb,
    const unsigned short* __restrict__ Wvb,
    unsigned short* __restrict__ Qb, unsigned short* __restrict__ Kb,
    unsigned short* __restrict__ Vb) {
  const int colBase = blockIdx.x * BN;
  const int rowBase = blockIdx.y * BM;
  const unsigned short* Bw;
  unsigned short* Cb;
  int ldc, ccol;
  if (colBase < 4096)      { Bw = Wqb + (size_t)colBase * HIDDEN;          Cb = Qb; ldc = 4096; ccol = colBase; }
  else if (colBase < 5120) { Bw = Wkb + (size_t)(colBase - 4096) * HIDDEN; Cb = Kb; ldc = 1024; ccol = colBase - 4096; }
  else                     { Bw = Wvb + (size_t)(colBase - 5120) * HIDDEN; Cb = Vb; ldc = 1024; ccol = colBase - 5120; }
  const unsigned short* A = Xb + (size_t)rowBase * HIDDEN;
  unsigned short* C = Cb + (size_t)rowBase * ldc + ccol;

  __shared__ unsigned short Abuf[3][BM * BK2];   // 3 x 16 KB
  __shared__ unsigned short Bbuf[3][BN * BK2];   // 3 x  8 KB

  const int tid = threadIdx.x;
  const int w = tid >> 6;          // 0..7
  const int lane = tid & 63;
  const int lrow = lane & 15;
  const int lk8 = lane >> 4;       // 0..3 (k-chunk within 32-K row)
  const int wr = (w >> 1) * 64;    // wave M base
  const int wc = (w & 1) * 64;     // wave N base
  const int lr16 = lane >> 2;      // staging: row within 16-row segment
  const int lp = lane & 3;         // staging: chunk position 0..3

  f32x4 acc[4][4];
#pragma unroll
  for (int i = 0; i < 4; i++)
#pragma unroll
    for (int j = 0; j < 4; j++) acc[i][j] = (f32x4){0.f, 0.f, 0.f, 0.f};

  // Stage one 1 KB segment (16 rows x 4 chunks of 16 B): LDS linear, source
  // swizzled: LDS chunk (r, p) holds global chunk (r, p ^ (r&3)).
#define STAGE_A2(bi, t, g) {                                                   \
    int seg = (g) * 8 + w;                     /* 0..15 */                     \
    int r = seg * 16 + lr16;                                                   \
    int c = lp ^ (r & 3);                                                      \
    gload16(&A[(size_t)r * HIDDEN + (t) * BK2 + c * 8], &Abuf[bi][seg * 512]); \
  }
#define STAGE_B2(bi, t) {                                                      \
    int seg = w;                               /* 0..7 */                      \
    int r = seg * 16 + lr16;                                                   \
    int c = lp ^ (r & 3);                                                      \
    gload16(&Bw[(size_t)r * HIDDEN + (t) * BK2 + c * 8], &Bbuf[bi][seg * 512]);\
  }
  // Fragment read: global chunk (r, lk8) sits at LDS chunk lk8 ^ (r&3).
#define RD_FRAG2(buf, rbase)                                                   \
  (*(const short8*)&(buf)[((rbase) + lrow) * 32 + ((lk8) ^ (((rbase) + lrow) & 3)) * 8])

  // ---- prologue: stage tiles 0 and 1 ----
  STAGE_A2(0, 0, 0); STAGE_A2(0, 0, 1); STAGE_B2(0, 0);
  STAGE_A2(1, 1, 0); STAGE_A2(1, 1, 1); STAGE_B2(1, 1);
  asm volatile("s_waitcnt vmcnt(3)" ::: "memory");  // tile0 resident
  __builtin_amdgcn_s_barrier();

  for (int t = 0; t < NKT2; t++) {
    const int bi = t % 3;
    const int bs = (t + 2) % 3;
    const bool st = (t + 2) < NKT2;
    const unsigned short* Ac = Abuf[bi];
    const unsigned short* Bc = Bbuf[bi];

    short8 afr[4], bfr[4];
#pragma unroll
    for (int m = 0; m < 4; m++) afr[m] = RD_FRAG2(Ac, wr + m * 16);
#pragma unroll
    for (int n = 0; n < 4; n++) bfr[n] = RD_FRAG2(Bc, wc + n * 16);
    if (st) { STAGE_A2(bs, t + 2, 0); STAGE_A2(bs, t + 2, 1); STAGE_B2(bs, t + 2); }
    __builtin_amdgcn_s_barrier();
    __builtin_amdgcn_s_setprio(1);
#pragma unroll
    for (int m = 0; m < 4; m++)
#pragma unroll
      for (int n = 0; n < 4; n++)
        acc[m][n] = __builtin_amdgcn_mfma_f32_16x16x32_bf16(afr[m], bfr[n], acc[m][n], 0, 0, 0);
    __builtin_amdgcn_s_setprio(0);
    if (st) asm volatile("s_waitcnt vmcnt(3)" ::: "memory");
    else    asm volatile("s_waitcnt vmcnt(0)" ::: "memory");
    __builtin_amdgcn_s_barrier();
  }
#undef STAGE_A2
#undef STAGE_B2
#undef RD_FRAG2

#pragma unroll
  for (int i = 0; i < 4; i++)
#pragma unroll
    for (int j = 0; j < 4; j++) {
      int col = wc + j * 16 + lrow;
#pragma unroll
      for (int r = 0; r < 4; r++) {
        int row = wr + i * 16 + lk8 * 4 + r;
        storeC(&C[(size_t)row * ldc + col], acc[i][j][r]);
      }
    }
}

// ---------------------------------------------------------------------------
// Round-4 core (gemm_out, unchanged): 256x128, BK=64, triple buffer 144 KB,
// 256 blocks = exact CU fill (this configuration measurably improved).
// ---------------------------------------------------------------------------
#define BK 64
#define NKT (HIDDEN / BK)   // 64 K-tiles

__global__ __launch_bounds__(512, 2) void gemm_out(
    const unsigned short* __restrict__ Ob, const unsigned short* __restrict__ Wob,
    float* __restrict__ C_) {
  const int colBase = blockIdx.x * BN;
  const int rowBase = blockIdx.y * BM;
  const unsigned short* A = Ob + (size_t)rowBase * HIDDEN;
  const unsigned short* B = Wob + (size_t)colBase * HIDDEN;
  float* C = C_ + (size_t)rowBase * HIDDEN + colBase;
  const int ldc = HIDDEN;

  __shared__ unsigned short Abuf[3][BM * BK];   // 3 x 32 KB
  __shared__ unsigned short Bbuf[3][BN * BK];   // 3 x 16 KB

  const int tid = threadIdx.x;
  const int w = tid >> 6;
  const int lane = tid & 63;
  const int lrow = lane & 15;
  const int lk8 = lane >> 4;
  const int wr = (w >> 1) * 64;
  const int wc = (w & 1) * 64;
  const int lr8 = lane >> 3;
  const int lp = lane & 7;

  f32x4 acc[4][4];
#pragma unroll
  for (int i = 0; i < 4; i++)
#pragma unroll
    for (int j = 0; j < 4; j++) acc[i][j] = (f32x4){0.f, 0.f, 0.f, 0.f};

#define STAGE_A(bi, t, g) {                                                  \
    int seg = (g) * 8 + w;                                                   \
    int r = seg * 8 + lr8;                                                   \
    int c = lp ^ (r & 7);                                                    \
    gload16(&A[(size_t)r * HIDDEN + (t) * BK + c * 8], &Abuf[bi][seg * 512]);\
  }
#define STAGE_B(bi, t, g) {                                                  \
    int seg = (g) * 8 + w;                                                   \
    int r = seg * 8 + lr8;                                                   \
    int c = lp ^ (r & 7);                                                    \
    gload16(&B[(size_t)r * HIDDEN + (t) * BK + c * 8], &Bbuf[bi][seg * 512]);\
  }
#define RD_FRAG(buf, rbase, ks)                                              \
  (*(const short8*)&(buf)[((rbase) + lrow) * 64 + (((ks) * 4 + lk8) ^ (((rbase) + lrow) & 7)) * 8])

#pragma unroll
  for (int g = 0; g < 4; g++) STAGE_A(0, 0, g);
#pragma unroll
  for (int g = 0; g < 2; g++) STAGE_B(0, 0, g);
#pragma unroll
  for (int g = 0; g < 4; g++) STAGE_A(1, 1, g);
#pragma unroll
  for (int g = 0; g < 2; g++) STAGE_B(1, 1, g);
  asm volatile("s_waitcnt vmcnt(6)" ::: "memory");
  __builtin_amdgcn_s_barrier();

  for (int t = 0; t < NKT; t++) {
    const int bi = t % 3;
    const int bs = (t + 2) % 3;
    const bool st = (t + 2) < NKT;
    const unsigned short* Ac = Abuf[bi];
    const unsigned short* Bc = Bbuf[bi];

    short8 bfr[4][2], afr[2][2];

#pragma unroll
    for (int n = 0; n < 4; n++)
#pragma unroll
      for (int ks = 0; ks < 2; ks++)
        bfr[n][ks] = RD_FRAG(Bc, wc + n * 16, ks);
#pragma unroll
    for (int m = 0; m < 2; m++)
#pragma unroll
      for (int ks = 0; ks < 2; ks++)
        afr[m][ks] = RD_FRAG(Ac, wr + m * 16, ks);
    if (st) { STAGE_A(bs, t + 2, 0); STAGE_A(bs, t + 2, 1); STAGE_B(bs, t + 2, 0); }
    __builtin_amdgcn_s_barrier();
    __builtin_amdgcn_s_setprio(1);
#pragma unroll
    for (int m = 0; m < 2; m++)
#pragma unroll
      for (int n = 0; n < 4; n++)
#pragma unroll
        for (int ks = 0; ks < 2; ks++)
          acc[m][n] = __builtin_amdgcn_mfma_f32_16x16x32_bf16(afr[m][ks], bfr[n][ks], acc[m][n], 0, 0, 0);
    __builtin_amdgcn_s_setprio(0);
    __builtin_amdgcn_s_barrier();

#pragma unroll
    for (int m = 0; m < 2; m++)
#pragma unroll
      for (int ks = 0; ks < 2; ks++)
        afr[m][ks] = RD_FRAG(Ac, wr + (m + 2) * 16, ks);
    if (st) { STAGE_A(bs, t + 2, 2); STAGE_A(bs, t + 2, 3); STAGE_B(bs, t + 2, 1); }
    __builtin_amdgcn_s_barrier();
    __builtin_amdgcn_s_setprio(1);
#pragma unroll
    for (int m = 0; m < 2; m++)
#pragma unroll
      for (int n = 0; n < 4; n++)
#pragma unroll
        for (int ks = 0; ks < 2; ks++)
          acc[m + 2][n] = __builtin_amdgcn_mfma_f32_16x16x32_bf16(afr[m][ks], bfr[n][ks], acc[m + 2][n], 0, 0, 0);
    __builtin_amdgcn_s_setprio(0);
    if (st) asm volatile("s_waitcnt vmcnt(6)" ::: "memory");
    else    asm volatile("s_waitcnt vmcnt(0)" ::: "memory");
    __builtin_amdgcn_s_barrier();
  }
#undef STAGE_A
#undef STAGE_B
#undef RD_FRAG

#pragma unroll
  for (int i = 0; i < 4; i++)
#pragma unroll
    for (int j = 0; j < 4; j++) {
      int col = wc + j * 16 + lrow;
#pragma unroll
      for (int r = 0; r < 4; r++) {
        int row = wr + i * 16 + lk8 * 4 + r;
        storeC(&C[(size_t)row * ldc + col], acc[i][j][r]);
      }
    }
}

// ---------------------------------------------------------------------------
// RoPE on bf16 Q/K, writing PACKED tile layouts:
//   Qp: per (head, 16-query strip) contiguous 4 KB:
//       Qp[((h*128 + (s>>4))*16 + (s&15))*128 + d]
//   Kp: per (kv head, 64-key tile) contiguous 16 KB:
//       Kp[((kvh*32 + (s>>6))*64 + (s&63))*128 + d]
// Q additionally scaled by 1/sqrt(128) * log2(e)  (exp2-domain softmax).
// ---------------------------------------------------------------------------
#define QSCALE 0.12753102123752056f  // 0.08838834764831845 * 1.4426950408889634

__global__ void rope_kernel(const unsigned short* __restrict__ Q,
                            const unsigned short* __restrict__ K,
                            unsigned short* __restrict__ Qp,
                            unsigned short* __restrict__ Kp) {
  int idx = blockIdx.x * blockDim.x + threadIdx.x;
  int d = idx & 63;
  int sh = idx >> 6;
  int h = sh % (N_HEADS + N_KV);
  int s = sh / (N_HEADS + N_KV);
  if (s >= S_LEN) return;

  float freq = expf(-(float)d * (9.210340371976184f / 64.0f));
  float ang = (float)s * freq;
  float sn, cs;
  sincosf(ang, &sn, &cs);

  const unsigned short* src;
  unsigned short* dst;
  float sc_out;
  if (h < N_HEADS) {
    src = Q + ((size_t)s * N_HEADS + h) * HEAD_DIM;
    dst = Qp + (((size_t)h * 128 + (s >> 4)) * 16 + (s & 15)) * HEAD_DIM;
    sc_out = QSCALE;
  } else {
    int kvh = h - N_HEADS;
    src = K + ((size_t)s * N_KV + kvh) * HEAD_DIM;
    dst = Kp + (((size_t)kvh * 32 + (s >> 6)) * 64 + (s & 63)) * HEAD_DIM;
    sc_out = 1.0f;
  }

  float x1 = bf2f(src[d]);
  float x2 = bf2f(src[d + 64]);
  dst[d] = f2bf((x1 * cs - x2 * sn) * sc_out);
  dst[d + 64] = f2bf((x2 * cs + x1 * sn) * sc_out);
}

// ---------------------------------------------------------------------------
// V transpose into PACKED tiles: Vb [S,1024] -> Vp, per (kvh, 64-key tile)
// contiguous 16 KB of [128 dims][64 keys]:
//   Vp[((kvh*32 + kt)*128 + d)*64 + k]
// ---------------------------------------------------------------------------
__global__ __launch_bounds__(256) void transp_v(
    const unsigned short* __restrict__ Vb, unsigned short* __restrict__ Vp) {
  __shared__ unsigned short t[64][72];
  const int s0 = blockIdx.x * 64;   // key tile base
  const int c0 = blockIdx.y * 64;   // flat dim base (kvh*128 + d)
  const int kt = s0 >> 6;
  const int tid = threadIdx.x;
#pragma unroll
  for (int i = 0; i < 2; i++) {
    int c = tid + i * 256;
    int r = c >> 3, ch = c & 7;
    *(short8*)&t[r][ch * 8] = *(const short8*)&Vb[(size_t)(s0 + r) * 1024 + c0 + ch * 8];
  }
  __syncthreads();
#pragma unroll
  for (int i = 0; i < 4; i++) {
    int c = tid + i * 256;
    int orow = c >> 4, oc4 = (c & 15) * 4;
    int g = c0 + orow;               // flat dim
    int kvh = g >> 7, d = g & 127;
    ushort4 o;
    o.x = t[oc4 + 0][orow]; o.y = t[oc4 + 1][orow];
    o.z = t[oc4 + 2][orow]; o.w = t[oc4 + 3][orow];
    *(ushort4*)&Vp[(((size_t)kvh * 32 + kt) * 128 + d) * 64 + oc4] = o;
  }
}

// ---------------------------------------------------------------------------
// MFMA flash attention v5: occupancy-doubled (round-3 verified).
// Block = 64 queries x 1 head, 4 waves x 16 queries. K-tiles of 64.
// Grid 1024 -> 4 blocks/CU (LDS 40 KB), 16 waves/CU.
// ---------------------------------------------------------------------------
#define AK 64

__global__ __launch_bounds__(256, 4) void attn_mfma(
    const unsigned short* __restrict__ Qp, const unsigned short* __restrict__ Kp,
    const unsigned short* __restrict__ Vp, unsigned short* __restrict__ Ob) {
  const int b = blockIdx.x;
  const int h = b & 31;
  const int j = b >> 5;
  const int qt = (b < 512) ? j : (47 - j);   // 0..31, paired for balance
  const int kvh = h >> 2;

  const int tid = threadIdx.x;
  const int w = tid >> 6;
  const int lane = tid & 63;
  const int lrow = lane & 15;
  const int lk8 = lane >> 4;

  __shared__ unsigned short Ks[64 * 128];    // 16 KB, swizzled
  __shared__ unsigned short Vts[128 * 64];   // 16 KB, swizzled
  __shared__ unsigned short Ps[4 * 16 * 64]; // 8 KB, wave-private, swizzled
  unsigned short* Pw = &Ps[w * 16 * 64];

  // ---- Q fragments: wave w owns query strip qt*64 + w*16 .. +15 ----
  short8 qf[4];
  const int t0 = qt * 4 + w;                 // packed 16-query strip index
#pragma unroll
  for (int ks = 0; ks < 4; ks++)
    qf[ks] = *(const short8*)&Qp[(((size_t)h * 128 + t0) * 16 + lrow) * 128 +
                                 ks * 32 + lk8 * 8];

  f32x4 acc[8];  // O^T: [dim-tile], queries = lane&15
  float m_i = -1e30f, l_i = 0.f;
#pragma unroll
  for (int n = 0; n < 8; n++) acc[n] = (f32x4){0.f, 0.f, 0.f, 0.f};

  const int nkt = qt + 1;

  for (int kt = 0; kt < nkt; kt++) {
    const int kb = kt * AK;
    const unsigned short* Kt  = Kp + ((size_t)kvh * 32 + kt) * 8192;
    const unsigned short* Vtt = Vp + ((size_t)kvh * 32 + kt) * 8192;

    __syncthreads();  // all waves done reading previous tile
    // ---- Stage K + V^T (16 KB each) with swizzled contiguous sources ----
#pragma unroll
    for (int jj = 0; jj < 4; jj++) {
      int seg = w * 4 + jj;                 // 0..15, 1 KB LDS segment
      // K: lds slot (r = seg*4 + lk8, p = lrow) <- global chunk (r, p^(r&15))
      int kr = seg * 4 + lk8;
      int kc = lrow ^ (kr & 15);
      gload16(Kt + ((size_t)kr * 16 + kc) * 8, &Ks[seg * 512]);
      // Vt: lds slot (r = seg*8 + lane>>3, p = lane&7) <- chunk (r, p^(r&7))
      int vr = seg * 8 + (lane >> 3);
      int vc = (lane & 7) ^ (vr & 7);
      gload16(Vtt + ((size_t)vr * 8 + vc) * 8, &Vts[seg * 512]);
    }
    __syncthreads();  // barrier drains vmcnt -> staged data visible

    // ---- S^T = K Q^T ----
    f32x4 s[4];
#pragma unroll
    for (int n = 0; n < 4; n++) s[n] = (f32x4){0.f, 0.f, 0.f, 0.f};

#pragma unroll
    for (int ks = 0; ks < 4; ks++) {
      short8 kf[4];
#pragma unroll
      for (int n = 0; n < 4; n++)
        kf[n] = *(const short8*)&Ks[(n * 16 + lrow) * 128 + (((ks * 4 + lk8) ^ lrow)) * 8];
#pragma unroll
      for (int n = 0; n < 4; n++)
        s[n] = __builtin_amdgcn_mfma_f32_16x16x32_bf16(kf[n], qf[ks], s[n], 0, 0, 0);
    }

    // ---- Causal mask: rows=keys (lk8*4+r), cols=queries (lrow) ----
    const int wqb = qt * 64 + w * 16;
    if (kb + AK - 1 > wqb) {
      int query = wqb + lrow;
#pragma unroll
      for (int n = 0; n < 4; n++) {
        int keyb = kb + n * 16 + lk8 * 4;
#pragma unroll
        for (int r = 0; r < 4; r++)
          if (keyb + r > query) s[n][r] = -1e30f;
      }
    }

    // ---- Online softmax (exp2): 16 in-lane scores + 2 shuffles ----
    {
      float mx = -1e30f;
#pragma unroll
      for (int n = 0; n < 4; n++)
#pragma unroll
        for (int r = 0; r < 4; r++) mx = fmaxf(mx, s[n][r]);
      mx = fmaxf(mx, __shfl_xor(mx, 16, 64));
      mx = fmaxf(mx, __shfl_xor(mx, 32, 64));
      float mn = fmaxf(m_i, mx);
      float al = exp2f(m_i - mn);
      m_i = mn;
      float ls = 0.f;
#pragma unroll
      for (int n = 0; n < 4; n++)
#pragma unroll
        for (int r = 0; r < 4; r++) {
          float e = exp2f(s[n][r] - mn);
          s[n][r] = e;
          ls += e;
        }
      ls += __shfl_xor(ls, 16, 64);
      ls += __shfl_xor(ls, 32, 64);
      l_i = l_i * al + ls;
#pragma unroll
      for (int n = 0; n < 8; n++)
#pragma unroll
        for (int r = 0; r < 4; r++) acc[n][r] *= al;
    }

    // ---- P -> wave-private LDS [query][key], 16B-granular XOR swizzle ----
#pragma unroll
    for (int n = 0; n < 4; n++) {
      ushort4 pk;
      pk.x = f2bf(s[n][0]); pk.y = f2bf(s[n][1]);
      pk.z = f2bf(s[n][2]); pk.w = f2bf(s[n][3]);
      int c8 = n * 4 + lk8;                      // 8B chunk 0..15 in row
      int c16s = (c8 >> 1) ^ (lrow & 7);         // swizzled 16B slot
      *(ushort4*)&Pw[lrow * 64 + c16s * 8 + (c8 & 1) * 4] = pk;
    }

    // ---- O^T += V^T P^T ----
#pragma unroll
    for (int ks2 = 0; ks2 < 2; ks2++) {
      int c16s = (ks2 * 4 + lk8) ^ (lrow & 7);
      short8 pf = *(const short8*)&Pw[lrow * 64 + c16s * 8];
#pragma unroll
      for (int n = 0; n < 8; n++) {
        short8 vf = *(const short8*)&Vts[(n * 16 + lrow) * 64 +
                                         (((ks2 * 4 + lk8) ^ (lrow & 7))) * 8];
        acc[n] = __builtin_amdgcn_mfma_f32_16x16x32_bf16(vf, pf, acc[n], 0, 0, 0);
      }
    }
  }

  // ---- Epilogue: normalize, store O [s][h*128+d] ----
  {
    float inv = 1.0f / l_i;
    int row = qt * 64 + w * 16 + lrow;
#pragma unroll
    for (int n = 0; n < 8; n++) {
      ushort4 o;
      o.x = f2bf(acc[n][0] * inv); o.y = f2bf(acc[n][1] * inv);
      o.z = f2bf(acc[n][2] * inv); o.w = f2bf(acc[n][3] * inv);
      *(ushort4*)&Ob[(size_t)row * 4096 + h * 128 + n * 16 + lk8 * 4] = o;
    }
  }
}

// ---------------------------------------------------------------------------
extern "C" void kernel_launch(void* const* d_in, const int* in_sizes, int n_in,
                              void* d_out, int out_size, void* d_ws, size_t ws_size,
                              hipStream_t stream) {
  const float* X  = (const float*)d_in[0];
  const float* Wq = (const float*)d_in[1];
  const float* Wk = (const float*)d_in[2];
  const float* Wv = (const float*)d_in[3];
  const float* Wo = (const float*)d_in[4];
  float* out = (float*)d_out;

  char* p = (char*)d_ws;
  unsigned short* Qb  = (unsigned short*)p; p += (size_t)S_LEN * 4096 * 2;  // 16.8 MB
  unsigned short* Kb  = (unsigned short*)p; p += (size_t)S_LEN * 1024 * 2;  //  4.2 MB
  unsigned short* Vb  = (unsigned short*)p; p += (size_t)S_LEN * 1024 * 2;  //  4.2 MB
  unsigned short* Qp  = (unsigned short*)p; p += (size_t)S_LEN * 4096 * 2;  // 16.8 MB
  unsigned short* Kp  = (unsigned short*)p; p += (size_t)S_LEN * 1024 * 2;  //  4.2 MB
  unsigned short* Vp  = (unsigned short*)p; p += (size_t)S_LEN * 1024 * 2;  //  4.2 MB
  unsigned short* Xb  = (unsigned short*)p; p += (size_t)S_LEN * 4096 * 2;  // 16.8 MB
  unsigned short* Wqb = (unsigned short*)p; p += (size_t)4096 * 4096 * 2;   // 33.6 MB
  unsigned short* Wkb = (unsigned short*)p; p += (size_t)1024 * 4096 * 2;   //  8.4 MB
  unsigned short* Wvb = (unsigned short*)p; p += (size_t)1024 * 4096 * 2;   //  8.4 MB
  unsigned short* Ob  = Xb;   // Xb dead after gemm_qkv
  unsigned short* Wob = Wqb;  // Wqb dead after gemm_qkv

  // 1. fp32 -> bf16
  conv_bf16<<<(S_LEN * 4096 / 4 + 255) / 256, 256, 0, stream>>>(X, Xb, S_LEN * 4096);
  conv_bf16<<<(4096 * 4096 / 4 + 255) / 256, 256, 0, stream>>>(Wq, Wqb, 4096 * 4096);
  conv_bf16<<<(1024 * 4096 / 4 + 255) / 256, 256, 0, stream>>>(Wk, Wkb, 1024 * 4096);
  conv_bf16<<<(1024 * 4096 / 4 + 255) / 256, 256, 0, stream>>>(Wv, Wvb, 1024 * 4096);

  // 2. Fused QKV projection -> bf16 (BK=32 pipelined core, 2 blocks/CU)
  gemm_qkv<<<dim3(6144 / BN, S_LEN / BM), 512, 0, stream>>>(Xb, Wqb, Wkb, Wvb, Qb, Kb, Vb);

  // 3. RoPE -> packed Qp/Kp tile layouts (Q pre-scaled into exp2 domain)
  int rope_threads = S_LEN * (N_HEADS + N_KV) * 64;
  rope_kernel<<<rope_threads / 256, 256, 0, stream>>>(Qb, Kb, Qp, Kp);

  // 4. V transpose -> packed Vp tiles
  transp_v<<<dim3(S_LEN / 64, 1024 / 64), 256, 0, stream>>>(Vb, Vp);

  // 5. Convert Wo (into Wqb space)
  conv_bf16<<<(4096 * 4096 / 4 + 255) / 256, 256, 0, stream>>>(Wo, Wob, 4096 * 4096);

  // 6. MFMA flash attention v5 -> bf16 (into Xb space), 64-query blocks
  attn_mfma<<<1024, 256, 0, stream>>>(Qp, Kp, Vp, Ob);

  // 7. Output projection (256 blocks = exact CU fill)
  gemm_out<<<dim3(4096 / BN, S_LEN / BM), 512, 0, stream>>>(Ob, Wob, out);
}